// Round 17
// baseline (1016.657 us; speedup 1.0000x reference)
//
#include <hip/hip_runtime.h>
#include <hip/hip_bf16.h>
#include <stdint.h>

#define E_EDGES   500000
#define MBLK      32
#define NT        15625       // E / 32 exactly
#define GRIDP     1024        // persistent: 4 blocks/CU x 256 CU
#define EPSV      1e-5f

typedef unsigned short u16;
typedef __attribute__((ext_vector_type(8))) short short8;
typedef __attribute__((ext_vector_type(4))) float f32x4;
typedef __attribute__((ext_vector_type(2))) uint32_t u32x2;

__device__ __forceinline__ u16 f2bf(float f) {
  __hip_bfloat16 h = __float2bfloat16(f);   // RNE
  return *(u16*)&h;
}
__device__ __forceinline__ uint32_t pk2bf(float lo, float hi) {
  return (uint32_t)f2bf(lo) | ((uint32_t)f2bf(hi) << 16);
}

// ---------------- prep: weights -> bf16 B-fragment layout (R6-proven) ----------------
// w1f[((n16*14 + k32)*64 + lane)*8 + j] = bf16(W1[k32*32+(lane>>4)*8+j][n16*16+(lane&15)])
// w2f[((n16*16 + kb )*64 + lane)*8 + j] = bf16(W2[kb*32 +(lane>>4)*8+j][n16*16+(lane&15)])
__global__ void prep_weights(const float* __restrict__ W1, const float* __restrict__ W2,
                             u16* __restrict__ w1f, u16* __restrict__ w2f) {
  int idx = blockIdx.x * blockDim.x + threadIdx.x;
  if (idx < 32*14*64) {
    int lane = idx & 63; int t = idx >> 6; int k32 = t % 14; int n16 = t / 14;
    int n = n16*16 + (lane & 15); int k0 = k32*32 + (lane >> 4)*8;
    short8 pk;
#pragma unroll
    for (int j = 0; j < 8; ++j) pk[j] = (short)f2bf(W1[(size_t)(k0 + j)*512 + n]);
    *(short8*)&w1f[(size_t)idx * 8] = pk;
  } else if (idx < 32*14*64 + 8*16*64) {
    int i2 = idx - 32*14*64;
    int lane = i2 & 63; int t = i2 >> 6; int k32 = t % 16; int n16 = t / 16;
    int n = n16*16 + (lane & 15); int k0 = k32*32 + (lane >> 4)*8;
    short8 pk;
#pragma unroll
    for (int j = 0; j < 8; ++j) pk[j] = (short)f2bf(W2[(size_t)(k0 + j)*128 + n]);
    *(short8*)&w2f[(size_t)i2 * 8] = pk;
  }
}

// ---------------- fused persistent-plain: R6/R12 body in a grid-stride tile loop ----------------
// Tests the dispatch-throughput-cap theory: identical per-tile work, but 1024 long-lived
// blocks instead of 15625 short-lived ones. No state held across MFMA phases (R13 lesson).
// LDS (32 KB union): X [32][448] bf16 (28K, stride 896) -> H [32][512] bf16 (32K, stride 1024)
//                 -> Y [32][128] f32 (16K, stride 512) + stat partials at [16K..24K).
#define SWZ16(row, byte) ((byte) ^ (((row) & 7) << 4))

__global__ __launch_bounds__(256, 4)
void fused_kernel(const float* __restrict__ srcp, const float* __restrict__ destp,
                  const float* __restrict__ edgep, const float* __restrict__ up,
                  const int* __restrict__ batch, const float* __restrict__ b1,
                  const float* __restrict__ b2,
                  const u16* __restrict__ w1f, const u16* __restrict__ w2f,
                  float* __restrict__ outp,
                  float* __restrict__ sums0, float* __restrict__ sums2,
                  float* __restrict__ cntsh, int nshard) {
  const int tid  = threadIdx.x;
  const int lane = tid & 63;
  const int w    = tid >> 6;         // wave 0..3
  const int l15  = lane & 15, l4 = lane >> 4;

  __shared__ __align__(16) u16 lds[32*512];   // 32 KB
  char* ldsb = (char*)lds;

  const int srow = tid >> 3;          // 0..31 (stage map)
  const int c8   = (tid & 7) * 8;
  const int c4    = tid & 31;         // store map
  const int rbase = tid >> 5;         // 0..7

  for (int t = blockIdx.x; t < NT; t += GRIDP) {
    const long grow0 = (long)t * MBLK;

    __syncthreads();   // B0 — previous iteration's Y/stat-slot reads complete

    // ---- stage: X tile [32][448] f32 -> bf16 -> LDS
    {
      const long sgrow = grow0 + srow;
      const int  bat = batch[sgrow];
#pragma unroll
      for (int j = 0; j < 7; ++j) {
        const float* sp;
        if (j == 0)      sp = srcp  + sgrow*128 + c8;
        else if (j == 1) sp = srcp  + sgrow*128 + 64 + c8;
        else if (j == 2) sp = destp + sgrow*128 + c8;
        else if (j == 3) sp = destp + sgrow*128 + 64 + c8;
        else if (j == 4) sp = edgep + sgrow*128 + c8;
        else if (j == 5) sp = edgep + sgrow*128 + 64 + c8;
        else             sp = up + (size_t)bat*64 + c8;
        f32x4 t0 = *(const f32x4*)(sp);
        f32x4 t1 = *(const f32x4*)(sp + 4);
        u32x2 lohi0 = (u32x2){pk2bf(t0[0], t0[1]), pk2bf(t0[2], t0[3])};
        u32x2 lohi1 = (u32x2){pk2bf(t1[0], t1[1]), pk2bf(t1[2], t1[3])};
        char* dst = ldsb + srow*896 + SWZ16(srow, (j*64 + c8)*2);
        *(u32x2*)(dst)     = lohi0;
        *(u32x2*)(dst + 8) = lohi1;
      }
    }
    __syncthreads();   // B1 — X staged

    // ---- GEMM1: wave w owns n16 [w*8, w*8+8). acc1[2][8].
    f32x4 acc1[2][8];
#pragma unroll
    for (int nj = 0; nj < 8; ++nj) {
      float bv = b1[(w*8 + nj)*16 + l15];
      acc1[0][nj] = (f32x4){bv, bv, bv, bv};
      acc1[1][nj] = (f32x4){bv, bv, bv, bv};
    }

#pragma unroll 2
    for (int k32 = 0; k32 < 14; ++k32) {
      short8 a[2], b[8];
#pragma unroll
      for (int mi = 0; mi < 2; ++mi) {
        int row = mi*16 + l15;
        a[mi] = *(const short8*)(ldsb + row*896 + SWZ16(row, k32*64 + l4*16));
      }
#pragma unroll
      for (int nj = 0; nj < 8; ++nj)
        b[nj] = *(const short8*)&w1f[((size_t)((w*8 + nj)*14 + k32)*64 + lane)*8];
#pragma unroll
      for (int mi = 0; mi < 2; ++mi)
#pragma unroll
        for (int nj = 0; nj < 8; ++nj)
          acc1[mi][nj] = __builtin_amdgcn_mfma_f32_16x16x32_bf16(a[mi], b[nj], acc1[mi][nj], 0, 0, 0);
    }
    __syncthreads();   // B2 — X reads done, LDS becomes H

    // ---- epilogue 1: relu -> bf16 -> H [32][512]
#pragma unroll
    for (int nj = 0; nj < 8; ++nj) {
      int n = (w*8 + nj)*16 + l15;
#pragma unroll
      for (int mi = 0; mi < 2; ++mi)
#pragma unroll
        for (int rr = 0; rr < 4; ++rr) {
          int row = mi*16 + l4*4 + rr;
          *(u16*)(ldsb + row*1024 + SWZ16(row, n*2)) = f2bf(fmaxf(acc1[mi][nj][rr], 0.f));
        }
    }
    __syncthreads();   // B3 — H ready

    // ---- edge prefetch (drains after GEMM2 -> latency hidden)
    f32x4 ebuf[4];
#pragma unroll
    for (int p = 0; p < 4; ++p)
      ebuf[p] = *(const f32x4*)(edgep + (grow0 + rbase + p*8)*128 + c4*4);

    // ---- GEMM2: wave w owns out-cols [w*32, w*32+32). acc2[2][2].
    f32x4 acc2[2][2];
#pragma unroll
    for (int nj = 0; nj < 2; ++nj) {
      float bv = b2[(w*2 + nj)*16 + l15];
      acc2[0][nj] = (f32x4){bv, bv, bv, bv};
      acc2[1][nj] = (f32x4){bv, bv, bv, bv};
    }

#pragma unroll 4
    for (int kb = 0; kb < 16; ++kb) {
      short8 hb[2], wfr[2];
#pragma unroll
      for (int mi = 0; mi < 2; ++mi) {
        int row = mi*16 + l15;
        hb[mi] = *(const short8*)(ldsb + row*1024 + SWZ16(row, kb*64 + l4*16));
      }
#pragma unroll
      for (int nj = 0; nj < 2; ++nj)
        wfr[nj] = *(const short8*)&w2f[(((size_t)((w*2 + nj)*16 + kb))*64 + lane)*8];
#pragma unroll
      for (int mi = 0; mi < 2; ++mi)
#pragma unroll
        for (int nj = 0; nj < 2; ++nj)
          acc2[mi][nj] = __builtin_amdgcn_mfma_f32_16x16x32_bf16(hb[mi], wfr[nj], acc2[mi][nj], 0, 0, 0);
    }
    __syncthreads();   // B4 — H reads done, LDS becomes Y f32 [32][128]

    // ---- bounce Y through LDS (coalesced store + stats source)
#pragma unroll
    for (int mi = 0; mi < 2; ++mi)
#pragma unroll
      for (int nj = 0; nj < 2; ++nj) {
        int col = (w*2 + nj)*16 + l15;
#pragma unroll
        for (int rr = 0; rr < 4; ++rr) {
          int row = mi*16 + l4*4 + rr;
          *(float*)(ldsb + row*512 + SWZ16(row, col*4)) = acc2[mi][nj][rr];
        }
      }
    __syncthreads();   // B5 — Y ready

    // ---- store (+edge) and per-graph stats
    const int g0 = batch[grow0];
    const int g1 = batch[grow0 + MBLK - 1];
    const int sh = t & (nshard - 1);

    if (g0 == g1) {
      // fast path: single-graph block
      f32x4 s = (f32x4){0,0,0,0}, s2 = (f32x4){0,0,0,0};
#pragma unroll
      for (int p = 0; p < 4; ++p) {
        int row = rbase + p*8;
        f32x4 y = *(const f32x4*)(ldsb + row*512 + SWZ16(row, c4*16));
        y = y + ebuf[p];
        *(f32x4*)(outp + (grow0 + row)*128 + c4*4) = y;
        s = s + y; s2 = s2 + y*y;
      }
      // partials -> LDS [16K..24K): linear slot per (rbase,c4) — 32 B each
      int slot = 16384 + (rbase*32 + c4)*32;
      *(f32x4*)(ldsb + slot)      = s;
      *(f32x4*)(ldsb + slot + 16) = s2;
      __syncthreads();   // B6
      int c4r = tid >> 3, stat = (tid >> 2) & 1, cq = tid & 3;
      float v = 0.f;
#pragma unroll
      for (int r = 0; r < 8; ++r)
        v += *(const float*)(ldsb + 16384 + (r*32 + c4r)*32 + stat*16 + cq*4);
      float* dst = stat ? sums2 : sums0;
      atomicAdd(&dst[(size_t)sh*8192 + g0*128 + c4r*4 + cq], v);
      if (tid == 0) atomicAdd(&cntsh[sh*64 + g0], (float)MBLK);
    } else {
      // slow path: graph boundary inside block (rare: ~63/15625)
      f32x4 s = (f32x4){0,0,0,0}, s2 = (f32x4){0,0,0,0};
      float rc = 0.f; int gcur = -1;
#pragma unroll
      for (int p = 0; p < 4; ++p) {
        int row = rbase + p*8;
        int g = batch[grow0 + row];
        if (g != gcur) {
          if (gcur >= 0) {
#pragma unroll
            for (int c = 0; c < 4; ++c) {
              atomicAdd(&sums0[(size_t)sh*8192 + gcur*128 + c4*4 + c], s[c]);
              atomicAdd(&sums2[(size_t)sh*8192 + gcur*128 + c4*4 + c], s2[c]);
            }
            if (c4 == 0) atomicAdd(&cntsh[sh*64 + gcur], rc);
          }
          gcur = g; s = (f32x4){0,0,0,0}; s2 = (f32x4){0,0,0,0}; rc = 0.f;
        }
        f32x4 y = *(const f32x4*)(ldsb + row*512 + SWZ16(row, c4*16));
        y = y + ebuf[p];
        *(f32x4*)(outp + (grow0 + row)*128 + c4*4) = y;
        s = s + y; s2 = s2 + y*y; rc += 1.f;
      }
#pragma unroll
      for (int c = 0; c < 4; ++c) {
        atomicAdd(&sums0[(size_t)sh*8192 + gcur*128 + c4*4 + c], s[c]);
        atomicAdd(&sums2[(size_t)sh*8192 + gcur*128 + c4*4 + c], s2[c]);
      }
      if (c4 == 0) atomicAdd(&cntsh[sh*64 + gcur], rc);
    }
  }
}

// ---------------- finalize: combine shards -> scale/shift per (graph, dim) ----------------
__global__ void finalize_kernel(const float* __restrict__ sums0, const float* __restrict__ sums2,
                                const float* __restrict__ cntsh, int nshard,
                                const float* __restrict__ gnw, const float* __restrict__ gnb,
                                const float* __restrict__ ms,
                                float* __restrict__ scale, float* __restrict__ shift) {
  int idx = blockIdx.x*blockDim.x + threadIdx.x;
  if (idx >= 64*128) return;
  int g = idx >> 7, d = idx & 127;
  float s = 0.f, s2 = 0.f, c = 0.f;
  for (int sh = 0; sh < nshard; ++sh) {
    s  += sums0[(size_t)sh*8192 + idx];
    s2 += sums2[(size_t)sh*8192 + idx];
    c  += cntsh[sh*64 + g];
  }
  c = fmaxf(c, 1.0f);
  float mean = s / c;
  float mm = mean * ms[d];
  float var = fmaxf(s2 / c - 2.f*mm*mean + mm*mm, 0.f);
  float sc = gnw[d] / sqrtf(var + EPSV);
  scale[idx] = sc;
  shift[idx] = gnb[d] - mm*sc;
}

// ---------------- norm: in-place y = y*scale[g] + shift[g] ----------------
__global__ void norm_kernel(float* __restrict__ y, const int* __restrict__ batch,
                            const float* __restrict__ scale, const float* __restrict__ shift) {
  long i = (long)blockIdx.x*blockDim.x + threadIdx.x;
  const long n4 = (long)E_EDGES * 32;
  long stride = (long)gridDim.x*blockDim.x;
  for (; i < n4; i += stride) {
    long row = i >> 5;
    int dq = (int)(i & 31) << 2;
    int g = batch[row];
    f32x4 v = *(f32x4*)(y + i*4);
    f32x4 sc = *(const f32x4*)(scale + g*128 + dq);
    f32x4 sh = *(const f32x4*)(shift + g*128 + dq);
    v = v*sc + sh;
    *(f32x4*)(y + i*4) = v;
  }
}

extern "C" void kernel_launch(void* const* d_in, const int* in_sizes, int n_in,
                              void* d_out, int out_size, void* d_ws, size_t ws_size,
                              hipStream_t stream) {
  const float* srcp  = (const float*)d_in[0];
  const float* destp = (const float*)d_in[1];
  const float* edgep = (const float*)d_in[2];
  const float* up    = (const float*)d_in[3];
  const int*   batch = (const int*)d_in[4];
  const float* W1    = (const float*)d_in[5];
  const float* b1    = (const float*)d_in[6];
  const float* W2    = (const float*)d_in[7];
  const float* b2    = (const float*)d_in[8];
  const float* gnw   = (const float*)d_in[9];
  const float* gnb   = (const float*)d_in[10];
  const float* ms    = (const float*)d_in[11];
  float* outp = (float*)d_out;

  char* ws = (char*)d_ws;
  u16*   w1f   = (u16*)(ws + 0);          // 458752 B
  u16*   w2f   = (u16*)(ws + 458752);     // 131072 B -> 589824
  float* scale = (float*)(ws + 589824);   // 32768  -> 622592
  float* shift = (float*)(ws + 622592);   // 32768  -> 655360
  float* cntsh = (float*)(ws + 655360);   // 8192   -> 663552
  int nshard = 32;
  while (nshard > 1 && 663552 + (size_t)nshard*65536 > ws_size) nshard >>= 1;
  float* sums0 = (float*)(ws + 663552);
  float* sums2 = (float*)(ws + 663552 + (size_t)nshard*32768);

  hipMemsetAsync(ws + 655360, 0, 8192 + (size_t)nshard*65536, stream);
  prep_weights<<<dim3(144), dim3(256), 0, stream>>>(W1, W2, w1f, w2f);

  fused_kernel<<<dim3(GRIDP), dim3(256), 0, stream>>>(srcp, destp, edgep, up, batch,
                                                      b1, b2, w1f, w2f, outp,
                                                      sums0, sums2, cntsh, nshard);

  finalize_kernel<<<dim3(32), dim3(256), 0, stream>>>(sums0, sums2, cntsh, nshard,
                                                      gnw, gnb, ms, scale, shift);
  norm_kernel<<<dim3(2048), dim3(256), 0, stream>>>(outp, batch, scale, shift);
}

// Round 18
// 568.376 us; speedup vs baseline: 1.7887x; 1.7887x over previous
//
#include <hip/hip_runtime.h>
#include <hip/hip_bf16.h>
#include <stdint.h>

#define E_EDGES   500000
#define MBLK      32
#define NBLK      15625       // E / 32 exactly
#define EPSV      1e-5f

typedef unsigned short u16;
typedef __attribute__((ext_vector_type(8))) short short8;
typedef __attribute__((ext_vector_type(4))) float f32x4;
typedef __attribute__((ext_vector_type(2))) uint32_t u32x2;

__device__ __forceinline__ u16 f2bf(float f) {
  __hip_bfloat16 h = __float2bfloat16(f);   // RNE
  return *(u16*)&h;
}
__device__ __forceinline__ uint32_t pk2bf(float lo, float hi) {
  return (uint32_t)f2bf(lo) | ((uint32_t)f2bf(hi) << 16);
}

// ---------------- prep: weights -> bf16 B-fragment layout (R6-proven) ----------------
// w1f[((n16*14 + k32)*64 + lane)*8 + j] = bf16(W1[k32*32+(lane>>4)*8+j][n16*16+(lane&15)])
// w2f[((n16*16 + kb )*64 + lane)*8 + j] = bf16(W2[kb*32 +(lane>>4)*8+j][n16*16+(lane&15)])
__global__ void prep_weights(const float* __restrict__ W1, const float* __restrict__ W2,
                             u16* __restrict__ w1f, u16* __restrict__ w2f) {
  int idx = blockIdx.x * blockDim.x + threadIdx.x;
  if (idx < 32*14*64) {
    int lane = idx & 63; int t = idx >> 6; int k32 = t % 14; int n16 = t / 14;
    int n = n16*16 + (lane & 15); int k0 = k32*32 + (lane >> 4)*8;
    short8 pk;
#pragma unroll
    for (int j = 0; j < 8; ++j) pk[j] = (short)f2bf(W1[(size_t)(k0 + j)*512 + n]);
    *(short8*)&w1f[(size_t)idx * 8] = pk;
  } else if (idx < 32*14*64 + 8*16*64) {
    int i2 = idx - 32*14*64;
    int lane = i2 & 63; int t = i2 >> 6; int k32 = t % 16; int n16 = t / 16;
    int n = n16*16 + (lane & 15); int k0 = k32*32 + (lane >> 4)*8;
    short8 pk;
#pragma unroll
    for (int j = 0; j < 8; ++j) pk[j] = (short)f2bf(W2[(size_t)(k0 + j)*128 + n]);
    *(short8*)&w2f[(size_t)i2 * 8] = pk;
  }
}

// ---------------- fused: Y = relu(X@W1+b1)@W2 + b2 + edge, + per-graph stats ----------------
// Best-measured configuration (R12): R6 structure (4 waves, 6 barriers, 32 KB LDS)
// + register-rotated weight prefetch in both GEMMs.
// LDS (32 KB union): X [32][448] bf16 (28K, stride 896) -> H [32][512] bf16 (32K, stride 1024)
//                 -> Y [32][128] f32 (16K, stride 512) + stat partials at [16K..24K).
#define SWZ16(row, byte) ((byte) ^ (((row) & 7) << 4))

__global__ __launch_bounds__(256, 3)
void fused_kernel(const float* __restrict__ srcp, const float* __restrict__ destp,
                  const float* __restrict__ edgep, const float* __restrict__ up,
                  const int* __restrict__ batch, const float* __restrict__ b1,
                  const float* __restrict__ b2,
                  const u16* __restrict__ w1f, const u16* __restrict__ w2f,
                  float* __restrict__ outp,
                  float* __restrict__ sums0, float* __restrict__ sums2,
                  float* __restrict__ cntsh, int nshard) {
  const int tid  = threadIdx.x;
  const int lane = tid & 63;
  const int w    = tid >> 6;         // wave 0..3
  const int l15  = lane & 15, l4 = lane >> 4;

  __shared__ __align__(16) u16 lds[32*512];   // 32 KB
  char* ldsb = (char*)lds;

  const long grow0 = (long)blockIdx.x * MBLK;

  // ---- stage: X tile [32][448] f32 -> bf16 -> LDS (one barrier)
  {
    const int srow = tid >> 3;          // 0..31
    const int c8   = (tid & 7) * 8;
    const long sgrow = grow0 + srow;
    const int  bat = batch[sgrow];
#pragma unroll
    for (int j = 0; j < 7; ++j) {
      const float* sp;
      if (j == 0)      sp = srcp  + sgrow*128 + c8;
      else if (j == 1) sp = srcp  + sgrow*128 + 64 + c8;
      else if (j == 2) sp = destp + sgrow*128 + c8;
      else if (j == 3) sp = destp + sgrow*128 + 64 + c8;
      else if (j == 4) sp = edgep + sgrow*128 + c8;
      else if (j == 5) sp = edgep + sgrow*128 + 64 + c8;
      else             sp = up + (size_t)bat*64 + c8;
      f32x4 t0 = *(const f32x4*)(sp);
      f32x4 t1 = *(const f32x4*)(sp + 4);
      u32x2 lohi0 = (u32x2){pk2bf(t0[0], t0[1]), pk2bf(t0[2], t0[3])};
      u32x2 lohi1 = (u32x2){pk2bf(t1[0], t1[1]), pk2bf(t1[2], t1[3])};
      char* dst = ldsb + srow*896 + SWZ16(srow, (j*64 + c8)*2);
      *(u32x2*)(dst)     = lohi0;
      *(u32x2*)(dst + 8) = lohi1;
    }
  }
  __syncthreads();   // B1 — X staged

  // ---- GEMM1: wave w owns n16 [w*8, w*8+8). acc1[2][8]. Weight double-buffer bA/bB.
  f32x4 acc1[2][8];
#pragma unroll
  for (int nj = 0; nj < 8; ++nj) {
    float bv = b1[(w*8 + nj)*16 + l15];
    acc1[0][nj] = (f32x4){bv, bv, bv, bv};
    acc1[1][nj] = (f32x4){bv, bv, bv, bv};
  }

  {
    short8 bA[8], bB[8];
#pragma unroll
    for (int nj = 0; nj < 8; ++nj)
      bA[nj] = *(const short8*)&w1f[((size_t)((w*8 + nj)*14 + 0)*64 + lane)*8];

#pragma unroll 1
    for (int kk = 0; kk < 7; ++kk) {
      int k32 = kk*2;
      // prefetch k32+1 into bB while MFMAs consume bA
#pragma unroll
      for (int nj = 0; nj < 8; ++nj)
        bB[nj] = *(const short8*)&w1f[((size_t)((w*8 + nj)*14 + (k32+1))*64 + lane)*8];
      {
        short8 a[2];
#pragma unroll
        for (int mi = 0; mi < 2; ++mi) {
          int row = mi*16 + l15;
          a[mi] = *(const short8*)(ldsb + row*896 + SWZ16(row, k32*64 + l4*16));
        }
#pragma unroll
        for (int mi = 0; mi < 2; ++mi)
#pragma unroll
          for (int nj = 0; nj < 8; ++nj)
            acc1[mi][nj] = __builtin_amdgcn_mfma_f32_16x16x32_bf16(a[mi], bA[nj], acc1[mi][nj], 0, 0, 0);
      }
      // prefetch k32+2 into bA while MFMAs consume bB
      if (kk < 6) {
#pragma unroll
        for (int nj = 0; nj < 8; ++nj)
          bA[nj] = *(const short8*)&w1f[((size_t)((w*8 + nj)*14 + (k32+2))*64 + lane)*8];
      }
      {
        short8 a[2];
#pragma unroll
        for (int mi = 0; mi < 2; ++mi) {
          int row = mi*16 + l15;
          a[mi] = *(const short8*)(ldsb + row*896 + SWZ16(row, (k32+1)*64 + l4*16));
        }
#pragma unroll
        for (int mi = 0; mi < 2; ++mi)
#pragma unroll
          for (int nj = 0; nj < 8; ++nj)
            acc1[mi][nj] = __builtin_amdgcn_mfma_f32_16x16x32_bf16(a[mi], bB[nj], acc1[mi][nj], 0, 0, 0);
      }
    }
  }
  __syncthreads();   // B2 — X reads done, LDS becomes H

  // ---- epilogue 1: relu -> bf16 -> H [32][512]
#pragma unroll
  for (int nj = 0; nj < 8; ++nj) {
    int n = (w*8 + nj)*16 + l15;
#pragma unroll
    for (int mi = 0; mi < 2; ++mi)
#pragma unroll
      for (int rr = 0; rr < 4; ++rr) {
        int row = mi*16 + l4*4 + rr;
        *(u16*)(ldsb + row*1024 + SWZ16(row, n*2)) = f2bf(fmaxf(acc1[mi][nj][rr], 0.f));
      }
  }
  __syncthreads();   // B3 — H ready

  // ---- edge prefetch (drains after GEMM2 -> latency hidden)
  const int c4    = tid & 31;      // 16B col-quad
  const int rbase = tid >> 5;      // 0..7
  f32x4 ebuf[4];
#pragma unroll
  for (int p = 0; p < 4; ++p)
    ebuf[p] = *(const f32x4*)(edgep + (grow0 + rbase + p*8)*128 + c4*4);

  // ---- GEMM2: wave w owns out-cols [w*32, w*32+32). acc2[2][2]. Weight double-buffer.
  f32x4 acc2[2][2];
#pragma unroll
  for (int nj = 0; nj < 2; ++nj) {
    float bv = b2[(w*2 + nj)*16 + l15];
    acc2[0][nj] = (f32x4){bv, bv, bv, bv};
    acc2[1][nj] = (f32x4){bv, bv, bv, bv};
  }

  {
    short8 wA[2], wB[2];
#pragma unroll
    for (int nj = 0; nj < 2; ++nj)
      wA[nj] = *(const short8*)&w2f[(((size_t)((w*2 + nj)*16 + 0))*64 + lane)*8];

#pragma unroll 1
    for (int kkb = 0; kkb < 8; ++kkb) {
      int kb = kkb*2;
#pragma unroll
      for (int nj = 0; nj < 2; ++nj)
        wB[nj] = *(const short8*)&w2f[(((size_t)((w*2 + nj)*16 + (kb+1)))*64 + lane)*8];
      {
        short8 hb[2];
#pragma unroll
        for (int mi = 0; mi < 2; ++mi) {
          int row = mi*16 + l15;
          hb[mi] = *(const short8*)(ldsb + row*1024 + SWZ16(row, kb*64 + l4*16));
        }
#pragma unroll
        for (int mi = 0; mi < 2; ++mi)
#pragma unroll
          for (int nj = 0; nj < 2; ++nj)
            acc2[mi][nj] = __builtin_amdgcn_mfma_f32_16x16x32_bf16(hb[mi], wA[nj], acc2[mi][nj], 0, 0, 0);
      }
      if (kkb < 7) {
#pragma unroll
        for (int nj = 0; nj < 2; ++nj)
          wA[nj] = *(const short8*)&w2f[(((size_t)((w*2 + nj)*16 + (kb+2)))*64 + lane)*8];
      }
      {
        short8 hb[2];
#pragma unroll
        for (int mi = 0; mi < 2; ++mi) {
          int row = mi*16 + l15;
          hb[mi] = *(const short8*)(ldsb + row*1024 + SWZ16(row, (kb+1)*64 + l4*16));
        }
#pragma unroll
        for (int mi = 0; mi < 2; ++mi)
#pragma unroll
          for (int nj = 0; nj < 2; ++nj)
            acc2[mi][nj] = __builtin_amdgcn_mfma_f32_16x16x32_bf16(hb[mi], wB[nj], acc2[mi][nj], 0, 0, 0);
      }
    }
  }
  __syncthreads();   // B4 — H reads done, LDS becomes Y f32 [32][128]

  // ---- bounce Y through LDS (coalesced store + stats source)
#pragma unroll
  for (int mi = 0; mi < 2; ++mi)
#pragma unroll
    for (int nj = 0; nj < 2; ++nj) {
      int col = (w*2 + nj)*16 + l15;
#pragma unroll
      for (int rr = 0; rr < 4; ++rr) {
        int row = mi*16 + l4*4 + rr;
        *(float*)(ldsb + row*512 + SWZ16(row, col*4)) = acc2[mi][nj][rr];
      }
    }
  __syncthreads();   // B5 — Y ready

  // ---- store (+edge) and per-graph stats
  const int g0 = batch[grow0];
  const int g1 = batch[grow0 + MBLK - 1];
  const int sh = blockIdx.x & (nshard - 1);

  if (g0 == g1) {
    // fast path: single-graph block
    f32x4 s = (f32x4){0,0,0,0}, s2 = (f32x4){0,0,0,0};
#pragma unroll
    for (int p = 0; p < 4; ++p) {
      int row = rbase + p*8;
      f32x4 y = *(const f32x4*)(ldsb + row*512 + SWZ16(row, c4*16));
      y = y + ebuf[p];
      *(f32x4*)(outp + (grow0 + row)*128 + c4*4) = y;
      s = s + y; s2 = s2 + y*y;
    }
    // partials -> LDS [16K..24K): linear slot per (rbase,c4) — 32 B each
    int slot = 16384 + (rbase*32 + c4)*32;
    *(f32x4*)(ldsb + slot)      = s;
    *(f32x4*)(ldsb + slot + 16) = s2;
    __syncthreads();   // B6
    int c4r = tid >> 3, stat = (tid >> 2) & 1, cq = tid & 3;
    float v = 0.f;
#pragma unroll
    for (int r = 0; r < 8; ++r)
      v += *(const float*)(ldsb + 16384 + (r*32 + c4r)*32 + stat*16 + cq*4);
    float* dst = stat ? sums2 : sums0;
    atomicAdd(&dst[(size_t)sh*8192 + g0*128 + c4r*4 + cq], v);
    if (tid == 0) atomicAdd(&cntsh[sh*64 + g0], (float)MBLK);
  } else {
    // slow path: graph boundary inside block (rare)
    f32x4 s = (f32x4){0,0,0,0}, s2 = (f32x4){0,0,0,0};
    float rc = 0.f; int gcur = -1;
#pragma unroll
    for (int p = 0; p < 4; ++p) {
      int row = rbase + p*8;
      int g = batch[grow0 + row];
      if (g != gcur) {
        if (gcur >= 0) {
#pragma unroll
          for (int c = 0; c < 4; ++c) {
            atomicAdd(&sums0[(size_t)sh*8192 + gcur*128 + c4*4 + c], s[c]);
            atomicAdd(&sums2[(size_t)sh*8192 + gcur*128 + c4*4 + c], s2[c]);
          }
          if (c4 == 0) atomicAdd(&cntsh[sh*64 + gcur], rc);
        }
        gcur = g; s = (f32x4){0,0,0,0}; s2 = (f32x4){0,0,0,0}; rc = 0.f;
      }
      f32x4 y = *(const f32x4*)(ldsb + row*512 + SWZ16(row, c4*16));
      y = y + ebuf[p];
      *(f32x4*)(outp + (grow0 + row)*128 + c4*4) = y;
      s = s + y; s2 = s2 + y*y; rc += 1.f;
    }
#pragma unroll
    for (int c = 0; c < 4; ++c) {
      atomicAdd(&sums0[(size_t)sh*8192 + gcur*128 + c4*4 + c], s[c]);
      atomicAdd(&sums2[(size_t)sh*8192 + gcur*128 + c4*4 + c], s2[c]);
    }
    if (c4 == 0) atomicAdd(&cntsh[sh*64 + gcur], rc);
  }
}

// ---------------- finalize: combine shards -> scale/shift per (graph, dim) ----------------
__global__ void finalize_kernel(const float* __restrict__ sums0, const float* __restrict__ sums2,
                                const float* __restrict__ cntsh, int nshard,
                                const float* __restrict__ gnw, const float* __restrict__ gnb,
                                const float* __restrict__ ms,
                                float* __restrict__ scale, float* __restrict__ shift) {
  int idx = blockIdx.x*blockDim.x + threadIdx.x;
  if (idx >= 64*128) return;
  int g = idx >> 7, d = idx & 127;
  float s = 0.f, s2 = 0.f, c = 0.f;
  for (int sh = 0; sh < nshard; ++sh) {
    s  += sums0[(size_t)sh*8192 + idx];
    s2 += sums2[(size_t)sh*8192 + idx];
    c  += cntsh[sh*64 + g];
  }
  c = fmaxf(c, 1.0f);
  float mean = s / c;
  float mm = mean * ms[d];
  float var = fmaxf(s2 / c - 2.f*mm*mean + mm*mm, 0.f);
  float sc = gnw[d] / sqrtf(var + EPSV);
  scale[idx] = sc;
  shift[idx] = gnb[d] - mm*sc;
}

// ---------------- norm: in-place y = y*scale[g] + shift[g] ----------------
__global__ void norm_kernel(float* __restrict__ y, const int* __restrict__ batch,
                            const float* __restrict__ scale, const float* __restrict__ shift) {
  long i = (long)blockIdx.x*blockDim.x + threadIdx.x;
  const long n4 = (long)E_EDGES * 32;
  long stride = (long)gridDim.x*blockDim.x;
  for (; i < n4; i += stride) {
    long row = i >> 5;
    int dq = (int)(i & 31) << 2;
    int g = batch[row];
    f32x4 v = *(f32x4*)(y + i*4);
    f32x4 sc = *(const f32x4*)(scale + g*128 + dq);
    f32x4 sh = *(const f32x4*)(shift + g*128 + dq);
    v = v*sc + sh;
    *(f32x4*)(y + i*4) = v;
  }
}

extern "C" void kernel_launch(void* const* d_in, const int* in_sizes, int n_in,
                              void* d_out, int out_size, void* d_ws, size_t ws_size,
                              hipStream_t stream) {
  const float* srcp  = (const float*)d_in[0];
  const float* destp = (const float*)d_in[1];
  const float* edgep = (const float*)d_in[2];
  const float* up    = (const float*)d_in[3];
  const int*   batch = (const int*)d_in[4];
  const float* W1    = (const float*)d_in[5];
  const float* b1    = (const float*)d_in[6];
  const float* W2    = (const float*)d_in[7];
  const float* b2    = (const float*)d_in[8];
  const float* gnw   = (const float*)d_in[9];
  const float* gnb   = (const float*)d_in[10];
  const float* ms    = (const float*)d_in[11];
  float* outp = (float*)d_out;

  char* ws = (char*)d_ws;
  u16*   w1f   = (u16*)(ws + 0);          // 458752 B
  u16*   w2f   = (u16*)(ws + 458752);     // 131072 B -> 589824
  float* scale = (float*)(ws + 589824);   // 32768  -> 622592
  float* shift = (float*)(ws + 622592);   // 32768  -> 655360
  float* cntsh = (float*)(ws + 655360);   // 8192   -> 663552
  int nshard = 32;
  while (nshard > 1 && 663552 + (size_t)nshard*65536 > ws_size) nshard >>= 1;
  float* sums0 = (float*)(ws + 663552);
  float* sums2 = (float*)(ws + 663552 + (size_t)nshard*32768);

  hipMemsetAsync(ws + 655360, 0, 8192 + (size_t)nshard*65536, stream);
  prep_weights<<<dim3(144), dim3(256), 0, stream>>>(W1, W2, w1f, w2f);

  fused_kernel<<<dim3(NBLK), dim3(256), 0, stream>>>(srcp, destp, edgep, up, batch,
                                                     b1, b2, w1f, w2f, outp,
                                                     sums0, sums2, cntsh, nshard);

  finalize_kernel<<<dim3(32), dim3(256), 0, stream>>>(sums0, sums2, cntsh, nshard,
                                                      gnw, gnb, ms, scale, shift);
  norm_kernel<<<dim3(2048), dim3(256), 0, stream>>>(outp, batch, scale, shift);
}